// Round 6
// baseline (469.796 us; speedup 1.0000x reference)
//
#include <hip/hip_runtime.h>
#include <stdint.h>

#define E_TOTAL 160000
#define NODES   10000
#define FDIM    128
#define HDIM    128
#define WN      1024
#define CDIM    64
#define EPB     32
#define NTHR    256

typedef __bf16 bf16x8 __attribute__((ext_vector_type(8)));
typedef __bf16 bf16x4 __attribute__((ext_vector_type(4)));
typedef float  f32x4  __attribute__((ext_vector_type(4)));

#define MFMA16(a,b,c) __builtin_amdgcn_mfma_f32_16x16x32_bf16(a,b,c,0,0,0)

// ws layout: [0, 256K) W2B bf16 B-frags ; [512K, 544K) W1B ; [576K, +40K) cnt
#define WS_W1B (512*1024)
#define WS_CNT (576*1024)

__device__ __forceinline__ f32x4 ntload4(const float* p) {
    return __builtin_nontemporal_load((const f32x4*)p);
}

// ---------- prep: W1/W2 -> bf16 B-fragments (hi only) + zero out/cnt ----------
// Frag layout: [tile][ks][lane][8 bf16]; lane: n = tile*16+(lane&15), k = ks*32+(lane>>4)*8+j.
__global__ void prep_kernel(const float* __restrict__ W1, const float* __restrict__ W2,
                            __bf16* __restrict__ W1B, __bf16* __restrict__ W2B,
                            float* __restrict__ out_acc, int* __restrict__ cnt) {
    const int b   = blockIdx.x;
    const int tid = threadIdx.x;
    if (b < 72) {
        const float* W = (b < 64) ? W2 : W1;
        __bf16* outB   = (b < 64) ? W2B : W1B;
        const int N    = (b < 64) ? WN : HDIM;
        const int tile = (b < 64) ? b : (b - 64);
        const int lane = tid & 63, ks = tid >> 6;
        const int n  = tile * 16 + (lane & 15);
        const int k0 = ks * 32 + (lane >> 4) * 8;
        bf16x8 hi;
        #pragma unroll
        for (int j = 0; j < 8; ++j) hi[j] = (__bf16)W[(size_t)(k0 + j) * N + n];
        *(bf16x8*)(outB + ((size_t)(tile * 4 + ks) * 64 + lane) * 8) = hi;
    } else {
        const int zt = (b - 72) * NTHR + tid;
        const float4 z4 = make_float4(0.f, 0.f, 0.f, 0.f);
        for (int i = zt; i < NODES * CDIM / 4; i += 8 * NTHR) ((float4*)out_acc)[i] = z4;
        for (int i = zt; i < NODES; i += 8 * NTHR) cnt[i] = 0;
    }
}

// ---------- fused: gather + MLP + tensor product + scatter ----------
// 32 edges/block, 4 waves; wave th owns GEMM2 tiles [th*16, th*16+16) = path p=th,
// full K=128, all 32 edges. Fold factors per path; p1's sh1 factored to epilogue.
// All A-fragments come from fragment-direct bf16 LDS regions (zero cvt at consume).
__global__ __launch_bounds__(NTHR, 4)
void fused_edge_kernel(const float* __restrict__ x,
                       const int*   __restrict__ edge_index,
                       const float* __restrict__ edge_attr,
                       const float* __restrict__ edge_sh,
                       const float* __restrict__ fc_b1,
                       const float* __restrict__ fc_b2,
                       const __bf16* __restrict__ W1B,
                       const __bf16* __restrict__ W2B,
                       float* __restrict__ out_acc,
                       int*   __restrict__ cnt)
{
    // fold factors [6][u][e]: 0: a*sh0*x0 (p0) | 1: a*x0 (p1, *sh1 in epilogue)
    //                         2..4: a*sh0*x1_m (p2) | 5: a/sqrt3*dot (p3)
    __shared__ float s_f[6][16][EPB];                      // 12 KB; reused as dump
    __shared__ __align__(16) __bf16 s_attr[4 * 2 * 64 * 8]; // 8 KB  [f][g][lane][j]
    __shared__ __align__(16) __bf16 s_h   [4 * 2 * 64 * 8]; // 8 KB
    __shared__ float s_b2s[WN];                            // 4 KB
    __shared__ float s_sh1[3][36];
    __shared__ int   s_dst[EPB];

    const int tid  = threadIdx.x;
    const int w    = tid >> 6;
    const int th   = w;                   // path index for GEMM2
    const int lane = tid & 63;
    const int quad = lane >> 4;
    const int li   = lane & 15;
    const int e0   = blockIdx.x * EPB;

    // ---- phase 0a: geometry factors (wave w, lanes<32: u in [w*4, w*4+4)) ----
    if (lane < 32) {
        const int e  = lane;
        const int up = w * 4;
        const int ge = e0 + e;
        const int src = edge_index[ge];
        const f32x4 sh4 = ntload4(edge_sh + (size_t)ge * 4);
        if (tid < EPB) {
            const int d = edge_index[E_TOTAL + ge];
            s_dst[e] = d;
            atomicAdd(&cnt[d], 1);
            s_sh1[0][e] = sh4.y; s_sh1[1][e] = sh4.z; s_sh1[2][e] = sh4.w;
        }
        const float* xp = x + (size_t)src * CDIM;
        const float4 x0v = *(const float4*)(xp + up);
        const float4 xa  = *(const float4*)(xp + 16 + up * 3);
        const float4 xb  = *(const float4*)(xp + 16 + up * 3 + 4);
        const float4 xc  = *(const float4*)(xp + 16 + up * 3 + 8);
        const float x1v[4][3] = {
            {xa.x, xa.y, xa.z}, {xa.w, xb.x, xb.y},
            {xb.z, xb.w, xc.x}, {xc.y, xc.z, xc.w}};
        const float x0a[4] = {x0v.x, x0v.y, x0v.z, x0v.w};
        const float alpha = 0.17677669529663689f;           // 1/sqrt(2*MUL)
        const float ai3   = alpha * 0.57735026918962576f;   // alpha/sqrt(3)
        const float sh0 = sh4.x;
        #pragma unroll
        for (int j = 0; j < 4; ++j) {
            const int u = up + j;
            const float x0u = x0a[j];
            s_f[0][u][e] = alpha * sh0 * x0u;
            s_f[1][u][e] = alpha * x0u;
            s_f[2][u][e] = alpha * sh0 * x1v[j][0];
            s_f[3][u][e] = alpha * sh0 * x1v[j][1];
            s_f[4][u][e] = alpha * sh0 * x1v[j][2];
            s_f[5][u][e] = ai3 * (x1v[j][0]*sh4.y + x1v[j][1]*sh4.z + x1v[j][2]*sh4.w);
        }
    }
    // ---- phase 0b: attr -> fragment-direct bf16 LDS; stage fc_b2 ----
    #pragma unroll
    for (int t4 = 0; t4 < 4; ++t4) {
        const int t = tid + t4 * NTHR;                 // 32 e x 32 i4
        const int e = t >> 5, i4 = t & 31;
        const f32x4 v = ntload4(edge_attr + (size_t)(e0 + e) * FDIM + i4 * 4);
        const int f = i4 >> 3, j0 = (i4 & 1) * 4, qc = (i4 >> 1) & 3;
        const int g = e >> 4, lc = e & 15;
        bf16x4 bv = {(__bf16)v[0], (__bf16)v[1], (__bf16)v[2], (__bf16)v[3]};
        *(bf16x4*)(s_attr + (((f * 2 + g) * 64 + qc * 16 + lc) * 8 + j0)) = bv;
    }
    *(f32x4*)&s_b2s[tid * 4] = *(const f32x4*)(fc_b2 + tid * 4);
    __syncthreads();   // B1

    // ---- phase 1: GEMM1 (wave w -> n-tiles 2w, 2w+1), h -> frag-direct bf16 LDS ----
    {
        const int nt0 = w * 2;
        const float b1a = fc_b1[nt0 * 16 + li];
        const float b1b = fc_b1[(nt0 + 1) * 16 + li];
        bf16x8 A1[2][4];
        #pragma unroll
        for (int g = 0; g < 2; ++g)
            #pragma unroll
            for (int ks = 0; ks < 4; ++ks)
                A1[g][ks] = *(const bf16x8*)(s_attr + ((ks * 2 + g) * 64 + lane) * 8);
        #pragma unroll
        for (int nt2 = 0; nt2 < 2; ++nt2) {
            const int nt = nt0 + nt2;
            const float bias = nt2 ? b1b : b1a;
            bf16x8 Bf[4];
            #pragma unroll
            for (int ks = 0; ks < 4; ++ks)
                Bf[ks] = *(const bf16x8*)(W1B + ((size_t)(nt * 4 + ks) * 64 + lane) * 8);
            f32x4 acc[2];
            #pragma unroll
            for (int g = 0; g < 2; ++g) acc[g] = (f32x4){bias, bias, bias, bias};
            #pragma unroll
            for (int ks = 0; ks < 4; ++ks)
                #pragma unroll
                for (int g = 0; g < 2; ++g) acc[g] = MFMA16(A1[g][ks], Bf[ks], acc[g]);
            // h[e = g*16+quad*4+r][k = nt*16+li] -> frag addr
            const int f  = nt >> 1;
            const int qc = (2 * (nt & 1) + (li >> 3)) & 3;
            const int j  = li & 7;
            #pragma unroll
            for (int g = 0; g < 2; ++g)
                #pragma unroll
                for (int r = 0; r < 4; ++r)
                    s_h[((f * 2 + g) * 64 + qc * 16 + (quad * 4 + r)) * 8 + j] =
                        (__bf16)fmaxf(acc[g][r], 0.f);
        }
    }
    __syncthreads();   // B2: h complete

    // ---- phase 2: A2 fragments (zero VALU) ----
    bf16x8 A2[2][4];
    #pragma unroll
    for (int g = 0; g < 2; ++g)
        #pragma unroll
        for (int ks = 0; ks < 4; ++ks)
            A2[g][ks] = *(const bf16x8*)(s_h + ((ks * 2 + g) * 64 + lane) * 8);

    // ---- phase 3: GEMM2 (tiles th*16..th*16+15, full K) + TP fold ----
    f32x4 o0[2];       // th0 / th3
    f32x4 o1[2][3];    // th1 (t1 in [g][0]) / th2
    #pragma unroll
    for (int g = 0; g < 2; ++g) {
        o0[g] = (f32x4){0.f, 0.f, 0.f, 0.f};
        #pragma unroll
        for (int m = 0; m < 3; ++m) o1[g][m] = (f32x4){0.f, 0.f, 0.f, 0.f};
    }
    {
        const int tbase = th * 16;
        const char* Wp = (const char*)W2B + (size_t)tbase * 4096 + lane * 16;
        bf16x8 P[2][4];
        #pragma unroll
        for (int s = 0; s < 2; ++s)
            #pragma unroll
            for (int ks = 0; ks < 4; ++ks)
                P[s][ks] = *(const bf16x8*)(Wp + s * 4096 + ks * 1024);
        #pragma unroll
        for (int c = 0; c < 16; ++c) {
            const bf16x8 cur[4] = {P[c & 1][0], P[c & 1][1], P[c & 1][2], P[c & 1][3]};
            if (c + 2 < 16) {
                #pragma unroll
                for (int ks = 0; ks < 4; ++ks)
                    P[c & 1][ks] = *(const bf16x8*)(Wp + (size_t)(c + 2) * 4096 + ks * 1024);
            }
            const float b2v = s_b2s[(tbase + c) * 16 + li];
            f32x4 acc[2];
            #pragma unroll
            for (int g = 0; g < 2; ++g) acc[g] = (f32x4){b2v, b2v, b2v, b2v};
            #pragma unroll
            for (int ks = 0; ks < 4; ++ks)
                #pragma unroll
                for (int g = 0; g < 2; ++g) acc[g] = MFMA16(A2[g][ks], cur[ks], acc[g]);
            const int u = c;
            if (th == 0) {
                #pragma unroll
                for (int g = 0; g < 2; ++g)
                    o0[g] += *(const f32x4*)&s_f[0][u][g * 16 + quad * 4] * acc[g];
            } else if (th == 1) {
                #pragma unroll
                for (int g = 0; g < 2; ++g)
                    o1[g][0] += *(const f32x4*)&s_f[1][u][g * 16 + quad * 4] * acc[g];
            } else if (th == 2) {
                #pragma unroll
                for (int g = 0; g < 2; ++g)
                    #pragma unroll
                    for (int m = 0; m < 3; ++m)
                        o1[g][m] += *(const f32x4*)&s_f[2 + m][u][g * 16 + quad * 4] * acc[g];
            } else {
                #pragma unroll
                for (int g = 0; g < 2; ++g)
                    o0[g] += *(const f32x4*)&s_f[5][u][g * 16 + quad * 4] * acc[g];
            }
        }
        if (th == 1) {   // expand t1 -> o1[m] = t1 * sh1[m]  (order: m=2,1,0)
            #pragma unroll
            for (int g = 0; g < 2; ++g) {
                const f32x4 t1 = o1[g][0];
                o1[g][2] = t1 * *(const f32x4*)&s_sh1[2][g * 16 + quad * 4];
                o1[g][1] = t1 * *(const f32x4*)&s_sh1[1][g * 16 + quad * 4];
                o1[g][0] = t1 * *(const f32x4*)&s_sh1[0][g * 16 + quad * 4];
            }
        }
    }

    // ---- phase 4: merge partials (th3->th0 o0, th2->th1 o1); scatter ----
    __syncthreads();   // B4: all s_f reads done -> reuse as dump
    float* dmp0 = &s_f[0][0][0];        // [32][17] o0 partial from th3
    float* dmp1 = dmp0 + 32 * 17;       // [32][49] o1 partial from th2
    if (th == 3) {
        #pragma unroll
        for (int g = 0; g < 2; ++g)
            #pragma unroll
            for (int r = 0; r < 4; ++r)
                dmp0[(g * 16 + quad * 4 + r) * 17 + li] = o0[g][r];
    } else if (th == 2) {
        #pragma unroll
        for (int g = 0; g < 2; ++g)
            #pragma unroll
            for (int r = 0; r < 4; ++r) {
                float* row = dmp1 + (g * 16 + quad * 4 + r) * 49 + li * 3;
                row[0] = o1[g][0][r]; row[1] = o1[g][1][r]; row[2] = o1[g][2][r];
            }
    }
    __syncthreads();   // B5
    if (th == 0) {
        #pragma unroll
        for (int g = 0; g < 2; ++g)
            #pragma unroll
            for (int r = 0; r < 4; ++r) {
                const int e = g * 16 + quad * 4 + r;
                unsafeAtomicAdd(out_acc + (size_t)s_dst[e] * CDIM + li,
                                o0[g][r] + dmp0[e * 17 + li]);
            }
    } else if (th == 1) {
        #pragma unroll
        for (int g = 0; g < 2; ++g)
            #pragma unroll
            for (int r = 0; r < 4; ++r) {
                const int e = g * 16 + quad * 4 + r;
                float* op = out_acc + (size_t)s_dst[e] * CDIM + 16 + li * 3;
                const float* row = dmp1 + e * 49 + li * 3;
                unsafeAtomicAdd(op + 0, o1[g][0][r] + row[0]);
                unsafeAtomicAdd(op + 1, o1[g][1][r] + row[1]);
                unsafeAtomicAdd(op + 2, o1[g][2][r] + row[2]);
            }
    }
}

__global__ void finalize_kernel(const float* __restrict__ x,
                                const int*   __restrict__ cnt,
                                float*       __restrict__ out)
{
    const int idx = blockIdx.x * blockDim.x + threadIdx.x;
    if (idx < NODES * CDIM) {
        const int n = idx >> 6;
        const float c = (float)(cnt[n] > 1 ? cnt[n] : 1);
        out[idx] = out[idx] / c + x[idx];
    }
}

extern "C" void kernel_launch(void* const* d_in, const int* in_sizes, int n_in,
                              void* d_out, int out_size, void* d_ws, size_t ws_size,
                              hipStream_t stream) {
    (void)in_sizes; (void)n_in; (void)out_size; (void)ws_size;
    const float* x          = (const float*)d_in[0];
    const int*   edge_index = (const int*)  d_in[1];
    const float* edge_attr  = (const float*)d_in[2];
    const float* edge_sh    = (const float*)d_in[3];
    const float* fc_w1      = (const float*)d_in[4];
    const float* fc_b1      = (const float*)d_in[5];
    const float* fc_w2      = (const float*)d_in[6];
    const float* fc_b2      = (const float*)d_in[7];
    float*  out = (float*)d_out;
    __bf16* W2B = (__bf16*)d_ws;
    __bf16* W1B = (__bf16*)((char*)d_ws + WS_W1B);
    int*    cnt = (int*)((char*)d_ws + WS_CNT);

    prep_kernel<<<80, NTHR, 0, stream>>>(fc_w1, fc_w2, W1B, W2B, out, cnt);
    fused_edge_kernel<<<E_TOTAL / EPB, NTHR, 0, stream>>>(
        x, edge_index, edge_attr, edge_sh, fc_b1, fc_b2, W1B, W2B, out, cnt);
    finalize_kernel<<<(NODES * CDIM + NTHR - 1) / NTHR, NTHR, 0, stream>>>(x, cnt, out);
}

// Round 7
// 252.043 us; speedup vs baseline: 1.8640x; 1.8640x over previous
//
#include <hip/hip_runtime.h>
#include <stdint.h>

#define E_TOTAL 160000
#define NODES   10000
#define FDIM    128
#define HDIM    128
#define WN      1024
#define CDIM    64
#define EPB     32
#define NTHR    256

typedef __bf16 bf16x8 __attribute__((ext_vector_type(8)));
typedef __bf16 bf16x4 __attribute__((ext_vector_type(4)));
typedef float  f32x4  __attribute__((ext_vector_type(4)));

#define MFMA16(a,b,c) __builtin_amdgcn_mfma_f32_16x16x32_bf16(a,b,c,0,0,0)

// ws layout: [0, 256K) W2B bf16 B-frags ; [512K, 544K) W1B ; [576K, +40K) cnt
#define WS_W1B (512*1024)
#define WS_CNT (576*1024)

__device__ __forceinline__ f32x4 ntload4(const float* p) {
    return __builtin_nontemporal_load((const f32x4*)p);
}

// ---------- prep: W1/W2 -> bf16 B-fragments + zero out/cnt ----------
// Frag layout: [tile][ks][lane][8 bf16]; lane: n = tile*16+(lane&15), k = ks*32+(lane>>4)*8+j.
__global__ void prep_kernel(const float* __restrict__ W1, const float* __restrict__ W2,
                            __bf16* __restrict__ W1B, __bf16* __restrict__ W2B,
                            float* __restrict__ out_acc, int* __restrict__ cnt) {
    const int b   = blockIdx.x;
    const int tid = threadIdx.x;
    if (b < 72) {
        const float* W = (b < 64) ? W2 : W1;
        __bf16* outB   = (b < 64) ? W2B : W1B;
        const int N    = (b < 64) ? WN : HDIM;
        const int tile = (b < 64) ? b : (b - 64);
        const int lane = tid & 63, ks = tid >> 6;
        const int n  = tile * 16 + (lane & 15);
        const int k0 = ks * 32 + (lane >> 4) * 8;
        bf16x8 hi;
        #pragma unroll
        for (int j = 0; j < 8; ++j) hi[j] = (__bf16)W[(size_t)(k0 + j) * N + n];
        *(bf16x8*)(outB + ((size_t)(tile * 4 + ks) * 64 + lane) * 8) = hi;
    } else {
        const int zt = (b - 72) * NTHR + tid;
        const float4 z4 = make_float4(0.f, 0.f, 0.f, 0.f);
        for (int i = zt; i < NODES * CDIM / 4; i += 8 * NTHR) ((float4*)out_acc)[i] = z4;
        for (int i = zt; i < NODES; i += 8 * NTHR) cnt[i] = 0;
    }
}

// ---------- fused: gather + MLP + tensor product + scatter ----------
// 32 edges/block, 4 waves = (th = w>>1, kh = w&1).
// GEMM2: wave covers tiles [th*32, th*32+32) x K-half kh for all 32 edges (1-term bf16).
// th0 = paths p0 (->o0), p1 (->t1, expand x sh1); th1 = p2 (->o1), p3 (->o0).
// Fragment-direct bf16 LDS for attr/h: zero conversion VALU at consume points.
__global__ __launch_bounds__(NTHR, 4)
void fused_edge_kernel(const float* __restrict__ x,
                       const int*   __restrict__ edge_index,
                       const float* __restrict__ edge_attr,
                       const float* __restrict__ edge_sh,
                       const float* __restrict__ fc_b1,
                       const float* __restrict__ fc_b2,
                       const __bf16* __restrict__ W1B,
                       const __bf16* __restrict__ W2B,
                       float* __restrict__ out_acc,
                       int*   __restrict__ cnt)
{
    // fold factors [6][u][e]: 0: a*sh0*x0 (p0) | 1: a*x0 (p1, *sh1 in epilogue)
    //                         2..4: a*sh0*x1_m (p2) | 5: a/sqrt3*dot (p3)
    __shared__ float s_f[6][16][EPB];                  // 12 KB; reused as dump C
    __shared__ __align__(16) char s_ab[16384];         // s_attr[0,8K)+s_h[8K,16K); dump A/B
    __shared__ float s_b2s[WN];                        // 4 KB
    __shared__ float s_sh1[3][36];
    __shared__ int   s_dst[EPB];

    __bf16* s_attr = (__bf16*)s_ab;
    __bf16* s_h    = (__bf16*)(s_ab + 8192);

    const int tid  = threadIdx.x;
    const int w    = tid >> 6;
    const int th   = w >> 1;
    const int kh   = w & 1;
    const int lane = tid & 63;
    const int quad = lane >> 4;
    const int li   = lane & 15;
    const int e0   = blockIdx.x * EPB;

    // ---- phase 0a: geometry factors (wave w, lanes<32: u in [w*4, w*4+4)) ----
    if (lane < 32) {
        const int e  = lane;
        const int up = w * 4;
        const int ge = e0 + e;
        const int src = edge_index[ge];
        const f32x4 sh4 = ntload4(edge_sh + (size_t)ge * 4);
        if (tid < EPB) {
            const int d = edge_index[E_TOTAL + ge];
            s_dst[e] = d;
            atomicAdd(&cnt[d], 1);
            s_sh1[0][e] = sh4.y; s_sh1[1][e] = sh4.z; s_sh1[2][e] = sh4.w;
        }
        const float* xp = x + (size_t)src * CDIM;
        const float4 x0v = *(const float4*)(xp + up);
        const float4 xa  = *(const float4*)(xp + 16 + up * 3);
        const float4 xb  = *(const float4*)(xp + 16 + up * 3 + 4);
        const float4 xc  = *(const float4*)(xp + 16 + up * 3 + 8);
        const float x1v[4][3] = {
            {xa.x, xa.y, xa.z}, {xa.w, xb.x, xb.y},
            {xb.z, xb.w, xc.x}, {xc.y, xc.z, xc.w}};
        const float x0a[4] = {x0v.x, x0v.y, x0v.z, x0v.w};
        const float alpha = 0.17677669529663689f;           // 1/sqrt(2*MUL)
        const float ai3   = alpha * 0.57735026918962576f;   // alpha/sqrt(3)
        const float sh0 = sh4.x;
        #pragma unroll
        for (int j = 0; j < 4; ++j) {
            const int u = up + j;
            const float x0u = x0a[j];
            s_f[0][u][e] = alpha * sh0 * x0u;
            s_f[1][u][e] = alpha * x0u;
            s_f[2][u][e] = alpha * sh0 * x1v[j][0];
            s_f[3][u][e] = alpha * sh0 * x1v[j][1];
            s_f[4][u][e] = alpha * sh0 * x1v[j][2];
            s_f[5][u][e] = ai3 * (x1v[j][0]*sh4.y + x1v[j][1]*sh4.z + x1v[j][2]*sh4.w);
        }
    }
    // ---- phase 0b: attr -> fragment-direct bf16 LDS; stage fc_b2 ----
    #pragma unroll
    for (int t4 = 0; t4 < 4; ++t4) {
        const int t = tid + t4 * NTHR;                 // 32 e x 32 i4
        const int e = t >> 5, i4 = t & 31;
        const f32x4 v = ntload4(edge_attr + (size_t)(e0 + e) * FDIM + i4 * 4);
        const int f = i4 >> 3, j0 = (i4 & 1) * 4, qc = (i4 >> 1) & 3;
        const int g = e >> 4, lc = e & 15;
        bf16x4 bv = {(__bf16)v[0], (__bf16)v[1], (__bf16)v[2], (__bf16)v[3]};
        *(bf16x4*)(s_attr + (((f * 2 + g) * 64 + qc * 16 + lc) * 8 + j0)) = bv;
    }
    *(f32x4*)&s_b2s[tid * 4] = *(const f32x4*)(fc_b2 + tid * 4);
    __syncthreads();   // B1

    // ---- phase 1: GEMM1 1-term (wave w -> n-tiles 2w, 2w+1), h -> frag bf16 LDS ----
    {
        const int nt0 = w * 2;
        const float b1a = fc_b1[nt0 * 16 + li];
        const float b1b = fc_b1[(nt0 + 1) * 16 + li];
        bf16x8 A1[2][4];
        #pragma unroll
        for (int g = 0; g < 2; ++g)
            #pragma unroll
            for (int ks = 0; ks < 4; ++ks)
                A1[g][ks] = *(const bf16x8*)(s_attr + ((ks * 2 + g) * 64 + lane) * 8);
        #pragma unroll
        for (int nt2 = 0; nt2 < 2; ++nt2) {
            const int nt = nt0 + nt2;
            const float bias = nt2 ? b1b : b1a;
            bf16x8 Bf[4];
            #pragma unroll
            for (int ks = 0; ks < 4; ++ks)
                Bf[ks] = *(const bf16x8*)(W1B + ((size_t)(nt * 4 + ks) * 64 + lane) * 8);
            f32x4 acc[2];
            #pragma unroll
            for (int g = 0; g < 2; ++g) acc[g] = (f32x4){bias, bias, bias, bias};
            #pragma unroll
            for (int ks = 0; ks < 4; ++ks)
                #pragma unroll
                for (int g = 0; g < 2; ++g) acc[g] = MFMA16(A1[g][ks], Bf[ks], acc[g]);
            const int f  = nt >> 1;
            const int qc = (2 * (nt & 1) + (li >> 3)) & 3;
            const int j  = li & 7;
            #pragma unroll
            for (int g = 0; g < 2; ++g)
                #pragma unroll
                for (int r = 0; r < 4; ++r)
                    s_h[((f * 2 + g) * 64 + qc * 16 + (quad * 4 + r)) * 8 + j] =
                        (__bf16)fmaxf(acc[g][r], 0.f);
        }
    }
    __syncthreads();   // B2: h complete

    // ---- phase 2: A2 fragments (this wave's K-half; zero VALU) ----
    bf16x8 A2[2][2];   // [g][k2], global ks = kh*2 + k2
    #pragma unroll
    for (int g = 0; g < 2; ++g)
        #pragma unroll
        for (int k2 = 0; k2 < 2; ++k2)
            A2[g][k2] = *(const bf16x8*)(s_h + (((kh * 2 + k2) * 2 + g) * 64 + lane) * 8);

    // ---- phase 3: GEMM2 1-term + TP fold; depth-2 B prefetch; b2 from LDS ----
    f32x4 o0[2];       // p0 (th=0) or p3 (th=1)
    f32x4 o1[2][3];    // p1-t1 in [g][0] (th=0) or p2 (th=1)
    #pragma unroll
    for (int g = 0; g < 2; ++g) {
        o0[g] = (f32x4){0.f, 0.f, 0.f, 0.f};
        #pragma unroll
        for (int m = 0; m < 3; ++m) o1[g][m] = (f32x4){0.f, 0.f, 0.f, 0.f};
    }
    const int tbase = th * 32;
    const __bf16* Wp = W2B + ((size_t)(tbase * 4 + kh * 2) * 64 + lane) * 8;
    bf16x8 P[2][2];    // [stage][k2]; frag stride 512 bf16, tile stride 4*512
    #pragma unroll
    for (int s = 0; s < 2; ++s)
        #pragma unroll
        for (int k2 = 0; k2 < 2; ++k2)
            P[s][k2] = *(const bf16x8*)(Wp + (s * 4 + k2) * 512);

    #pragma unroll
    for (int half = 0; half < 2; ++half) {
        #pragma unroll
        for (int cc = 0; cc < 16; ++cc) {
            const int c = half * 16 + cc;
            const int u = cc;
            const bf16x8 b0 = P[c & 1][0];
            const bf16x8 b1 = P[c & 1][1];
            if (c + 2 < 32) {
                #pragma unroll
                for (int k2 = 0; k2 < 2; ++k2)
                    P[c & 1][k2] = *(const bf16x8*)(Wp + ((c + 2) * 4 + k2) * 512);
            }
            f32x4 acc[2];
            if (kh == 0) {
                const float b2v = s_b2s[(tbase + c) * 16 + li];
                acc[0] = (f32x4){b2v, b2v, b2v, b2v};
                acc[1] = acc[0];
            } else {
                acc[0] = (f32x4){0.f, 0.f, 0.f, 0.f};
                acc[1] = acc[0];
            }
            #pragma unroll
            for (int g = 0; g < 2; ++g) {
                acc[g] = MFMA16(A2[g][0], b0, acc[g]);
                acc[g] = MFMA16(A2[g][1], b1, acc[g]);
            }
            // fold: p = th*2 + half (tile-constant)
            if (th == 0) {
                if (half == 0) {
                    #pragma unroll
                    for (int g = 0; g < 2; ++g)
                        o0[g] += *(const f32x4*)&s_f[0][u][g * 16 + quad * 4] * acc[g];
                } else {
                    #pragma unroll
                    for (int g = 0; g < 2; ++g)
                        o1[g][0] += *(const f32x4*)&s_f[1][u][g * 16 + quad * 4] * acc[g];
                }
            } else {
                if (half == 0) {
                    #pragma unroll
                    for (int g = 0; g < 2; ++g)
                        #pragma unroll
                        for (int m = 0; m < 3; ++m)
                            o1[g][m] += *(const f32x4*)&s_f[2 + m][u][g * 16 + quad * 4] * acc[g];
                } else {
                    #pragma unroll
                    for (int g = 0; g < 2; ++g)
                        o0[g] += *(const f32x4*)&s_f[5][u][g * 16 + quad * 4] * acc[g];
                }
            }
        }
    }
    if (th == 0) {   // expand t1 -> o1[m] = t1 * sh1[m] (order m=2,1,0)
        #pragma unroll
        for (int g = 0; g < 2; ++g) {
            const f32x4 t1 = o1[g][0];
            o1[g][2] = t1 * *(const f32x4*)&s_sh1[2][g * 16 + quad * 4];
            o1[g][1] = t1 * *(const f32x4*)&s_sh1[1][g * 16 + quad * 4];
            o1[g][0] = t1 * *(const f32x4*)&s_sh1[0][g * 16 + quad * 4];
        }
    }

    // ---- phase 4: merge partials in LDS; single wave scatters ----
    __syncthreads();   // B4: all s_f / s_ab readers done
    float* regA = (float*)s_ab;           // kh1,th0: [e][64]
    float* regB = (float*)(s_ab + 8192);  // kh1,th1
    float* regC = &s_f[0][0][0];          // kh0,th1
    float* dump = (kh == 1) ? ((th == 0) ? regA : regB) : ((th == 1) ? regC : nullptr);
    if (dump) {
        #pragma unroll
        for (int g = 0; g < 2; ++g)
            #pragma unroll
            for (int r = 0; r < 4; ++r) {
                float* row = dump + (g * 16 + quad * 4 + r) * 64;
                row[li] = o0[g][r];
                #pragma unroll
                for (int m = 0; m < 3; ++m) row[16 + li * 3 + m] = o1[g][m][r];
            }
    }
    __syncthreads();   // B5
    if (kh == 0 && th == 0) {
        #pragma unroll
        for (int g = 0; g < 2; ++g)
            #pragma unroll
            for (int r = 0; r < 4; ++r) {
                const int e = g * 16 + quad * 4 + r;
                const float* rA = regA + e * 64;
                const float* rB = regB + e * 64;
                const float* rC = regC + e * 64;
                float* op = out_acc + (size_t)s_dst[e] * CDIM;
                unsafeAtomicAdd(&op[li], o0[g][r] + rA[li] + rB[li] + rC[li]);
                #pragma unroll
                for (int m = 0; m < 3; ++m) {
                    const int s = 16 + li * 3 + m;
                    unsafeAtomicAdd(&op[s], o1[g][m][r] + rA[s] + rB[s] + rC[s]);
                }
            }
    }
}

__global__ void finalize_kernel(const float* __restrict__ x,
                                const int*   __restrict__ cnt,
                                float*       __restrict__ out)
{
    const int idx = blockIdx.x * blockDim.x + threadIdx.x;
    if (idx < NODES * CDIM) {
        const int n = idx >> 6;
        const float c = (float)(cnt[n] > 1 ? cnt[n] : 1);
        out[idx] = out[idx] / c + x[idx];
    }
}

extern "C" void kernel_launch(void* const* d_in, const int* in_sizes, int n_in,
                              void* d_out, int out_size, void* d_ws, size_t ws_size,
                              hipStream_t stream) {
    (void)in_sizes; (void)n_in; (void)out_size; (void)ws_size;
    const float* x          = (const float*)d_in[0];
    const int*   edge_index = (const int*)  d_in[1];
    const float* edge_attr  = (const float*)d_in[2];
    const float* edge_sh    = (const float*)d_in[3];
    const float* fc_w1      = (const float*)d_in[4];
    const float* fc_b1      = (const float*)d_in[5];
    const float* fc_w2      = (const float*)d_in[6];
    const float* fc_b2      = (const float*)d_in[7];
    float*  out = (float*)d_out;
    __bf16* W2B = (__bf16*)d_ws;
    __bf16* W1B = (__bf16*)((char*)d_ws + WS_W1B);
    int*    cnt = (int*)((char*)d_ws + WS_CNT);

    prep_kernel<<<80, NTHR, 0, stream>>>(fc_w1, fc_w2, W1B, W2B, out, cnt);
    fused_edge_kernel<<<E_TOTAL / EPB, NTHR, 0, stream>>>(
        x, edge_index, edge_attr, edge_sh, fc_b1, fc_b2, W1B, W2B, out, cnt);
    finalize_kernel<<<(NODES * CDIM + NTHR - 1) / NTHR, NTHR, 0, stream>>>(x, cnt, out);
}